// Round 6
// baseline (228.250 us; speedup 1.0000x reference)
//
#include <hip/hip_runtime.h>

#define HWSZ 65536      // H*W
#define KSEL 32768u     // int(0.5*H*W)
#define CCH  128        // channels
#define BN   4          // batch
#define NG   (CCH * BN) // 512 groups; group g = b*CCH + c, contiguous HWSZ floats
#define NT   1024       // threads per block (16 waves) -> 2 blocks/CU = 32 waves/CU
#define NW   (NT / 64)  // 16 waves
#define ITER (HWSZ / 4 / NT)   // 16 float4 iterations per pass

#define NB1  24                // coarse bins: b1 = q>>24 in [0,23] (q < 24*2^24 by e<=1/e)
#define NB2  1024              // fine bins inside boundary coarse bin (q>>14 & 1023)
#define NCP  4                 // hist2 copies (by wave) to cut same-address atomic serialization
#define QC   (-744261120.0f)   // -ln(2) * 2^30: q = (u32)(f1*log2(f1)*QC + 0.5)
#define SUMMASK ((1ull << 47) - 1ull)   // q30 sum bits[46:0], count bits[63:47]

// Two streaming passes. Phase 1 (HBM): exact q30 total + 24-bin coarse count
// hist in TWO u64 register SWARs (12 x 5-bit fields each, even/odd coarse bins,
// branchless select, flushed every 16 elements; max field 16 < 31). Phase 2
// (L3 re-read): exact q30 sum of coarse bins > cb in registers; boundary-bin
// elements (now ~half as many as with 12 coarse bins) hit a 1024-fine-bin
// packed (cnt<<47|q30) LDS atomic hist with 4 wave-interleaved copies
// (4x less same-address contention at the e_max density spike).
// Fine width 2^-16 in e — finer than the verified kernels; same exact-sum +
// in-bin-average interpolation => identical ranking numerics.
__global__ void __launch_bounds__(NT, 8) passA_kernel(
    const float* __restrict__ hsi, const float* __restrict__ wp,
    double* __restrict__ total_sum, double* __restrict__ topk_sum) {
    __shared__ unsigned long long hist2[NCP][NB2]; // 32 KB packed fine hist copies
    __shared__ unsigned wred[NW * 12];             // 768 B wave-level coarse counts
    __shared__ unsigned cnt1[NB1];                 // 96 B
    __shared__ unsigned long long wtot[NW];        // 128 B
    __shared__ unsigned long long whigh[NW];       // 128 B
    __shared__ int s_cb;
    __shared__ unsigned s_acc;                     // exact count strictly above bin cb
    __shared__ int s_fb;
    // total ~33.5 KB LDS -> 2 blocks/CU fine

    const int g    = blockIdx.x;
    const int tid  = threadIdx.x;
    const int lane = tid & 63;
    const int wid  = tid >> 6;
    const float w  = wp[0];

    for (int i = tid; i < NCP * NB2; i += NT)
        ((unsigned long long*)hist2)[i] = 0ull;    // consumed after phase-1 barrier

    const float4* __restrict__ src = (const float4*)(hsi + (size_t)g * HWSZ);

    // ---- Phase 1: HBM stream — exact q30 total + 2xSWAR 24-bin coarse hist ----
    unsigned long long tot = 0ull;
    unsigned aE0 = 0u, aE1 = 0u, aE2 = 0u, aE3 = 0u, aE4 = 0u, aE5 = 0u;  // even bins
    unsigned aO0 = 0u, aO1 = 0u, aO2 = 0u, aO3 = 0u, aO4 = 0u, aO5 = 0u;  // odd bins

    #pragma unroll 1
    for (int o = 0; o < 4; ++o) {                  // real loop: caps regs in flight
        unsigned long long sw0 = 0ull, sw1 = 0ull; // 12 x 5-bit fields each
        #pragma unroll
        for (int ii = 0; ii < 4; ++ii) {
            float4 v = src[(o * 4 + ii) * NT + tid];
            unsigned qs = 0u;                      // 4*q < 2^31: safe u32 batch
            #pragma unroll
            for (int j = 0; j < 4; ++j) {
                float f1 = (&v.x)[j] * w;
                float m  = f1 * __log2f(f1);       // v_log_f32 + v_mul
                unsigned q = (unsigned)fmaf(m, QC, 0.5f);  // e*2^30, q < 2^29
                qs += q;
                unsigned b1 = q >> 24;             // coarse bin, <= 23 always
                unsigned long long inc = 1ull << ((b1 >> 1) * 5);
                sw0 += (b1 & 1u) ? 0ull : inc;     // even bins -> sw0
                sw1 += (b1 & 1u) ? inc : 0ull;     // odd bins  -> sw1
            }
            tot += qs;
        }
        // flush SWARs (16 elements counted; max field 16 < 31)
        aE0 += (unsigned)( sw0        & 31u) | ((unsigned)((sw0 >>  5) & 31u) << 16);
        aE1 += (unsigned)((sw0 >> 10) & 31u) | ((unsigned)((sw0 >> 15) & 31u) << 16);
        aE2 += (unsigned)((sw0 >> 20) & 31u) | ((unsigned)((sw0 >> 25) & 31u) << 16);
        aE3 += (unsigned)((sw0 >> 30) & 31u) | ((unsigned)((sw0 >> 35) & 31u) << 16);
        aE4 += (unsigned)((sw0 >> 40) & 31u) | ((unsigned)((sw0 >> 45) & 31u) << 16);
        aE5 += (unsigned)((sw0 >> 50) & 31u) | ((unsigned)((sw0 >> 55) & 31u) << 16);
        aO0 += (unsigned)( sw1        & 31u) | ((unsigned)((sw1 >>  5) & 31u) << 16);
        aO1 += (unsigned)((sw1 >> 10) & 31u) | ((unsigned)((sw1 >> 15) & 31u) << 16);
        aO2 += (unsigned)((sw1 >> 20) & 31u) | ((unsigned)((sw1 >> 25) & 31u) << 16);
        aO3 += (unsigned)((sw1 >> 30) & 31u) | ((unsigned)((sw1 >> 35) & 31u) << 16);
        aO4 += (unsigned)((sw1 >> 40) & 31u) | ((unsigned)((sw1 >> 45) & 31u) << 16);
        aO5 += (unsigned)((sw1 >> 50) & 31u) | ((unsigned)((sw1 >> 55) & 31u) << 16);
    }

    // wave-level reductions (u16 fields: max 64 lanes * 64 el = 4096 < 65536)
    {
        unsigned accv[12] = {aE0, aE1, aE2, aE3, aE4, aE5,
                             aO0, aO1, aO2, aO3, aO4, aO5};
        #pragma unroll
        for (int k = 0; k < 12; ++k) {
            unsigned a = accv[k];
            #pragma unroll
            for (int off = 32; off > 0; off >>= 1) a += __shfl_down(a, off, 64);
            if (lane == 0) wred[wid * 12 + k] = a;
        }
    }
    #pragma unroll
    for (int off = 32; off > 0; off >>= 1) tot += __shfl_down(tot, off, 64);
    if (lane == 0) wtot[wid] = tot;
    __syncthreads();

    // ---- combine 16 waves -> cnt1[24] ----
    // coarse bin b: field f=b>>1 lives in acc[(b&1)*6 + (f>>1)], halfword f&1
    if (tid < NB1) {
        const unsigned f = (unsigned)tid >> 1;
        const unsigned idx = (tid & 1) * 6 + (f >> 1);
        const unsigned sh = (f & 1) * 16;
        unsigned s = 0u;
        #pragma unroll
        for (int ww = 0; ww < NW; ++ww)
            s += (wred[ww * 12 + idx] >> sh) & 0xFFFFu;
        cnt1[tid] = s;
    }
    __syncthreads();

    // ---- locate level-1 boundary bin cb (scan from the top; 24 bins) ----
    if (tid == 0) {
        unsigned acc = 0u;
        int b = NB1 - 1;
        for (; b > 0; --b) {
            unsigned c = cnt1[b];
            if (acc + c >= KSEL) break;
            acc += c;
        }
        s_cb = b;
        s_acc = acc;
    }
    __syncthreads();
    const unsigned cb = (unsigned)s_cb;
    unsigned long long* __restrict__ myh2 = hist2[wid & (NCP - 1)];

    // ---- Phase 2: L3-resident re-read — exact high sum + fine hist inside cb ----
    unsigned long long hsum = 0ull;
    #pragma unroll 1
    for (int o = 0; o < 4; ++o) {
        #pragma unroll
        for (int ii = 0; ii < 4; ++ii) {
            float4 v = src[(o * 4 + ii) * NT + tid];
            unsigned qs = 0u;
            #pragma unroll
            for (int j = 0; j < 4; ++j) {
                float f1 = (&v.x)[j] * w;
                float m  = f1 * __log2f(f1);
                unsigned q = (unsigned)fmaf(m, QC, 0.5f);  // bit-identical to phase 1
                unsigned b1 = q >> 24;
                qs += (b1 > cb) ? q : 0u;
                if (b1 == cb) {
                    unsigned fbin = (q >> 14) & (NB2 - 1); // exact: 2^24/2^14 = 1024
                    atomicAdd(&myh2[fbin], (1ull << 47) | (unsigned long long)q);
                }
            }
            hsum += qs;
        }
    }
    #pragma unroll
    for (int off = 32; off > 0; off >>= 1) hsum += __shfl_down(hsum, off, 64);
    if (lane == 0) whigh[wid] = hsum;
    __syncthreads();

    // ---- fold the NCP copies, then in-place parallel suffix scan ----
    {
        unsigned long long h = hist2[0][tid] + hist2[1][tid]
                             + hist2[2][tid] + hist2[3][tid];
        __syncthreads();
        hist2[0][tid] = h;                         // each thread touches only [.][tid]
    }
    __syncthreads();
    for (int off = 1; off < NB2; off <<= 1) {      // cnt 17b ok, sum < 2^45
        unsigned long long a = hist2[0][tid];
        unsigned long long b = (tid + off < NB2) ? hist2[0][tid + off] : 0ull;
        __syncthreads();
        hist2[0][tid] = a + b;
        __syncthreads();
    }
    const unsigned needed = KSEL - s_acc;          // >= 1 by construction of cb
    {
        unsigned c0 = (unsigned)(hist2[0][tid] >> 47);
        unsigned c1 = (tid == NB2 - 1) ? 0u : (unsigned)(hist2[0][tid + 1] >> 47);
        if (c0 >= needed && c1 < needed) s_fb = tid;   // unique crossing: non-increasing
    }
    __syncthreads();

    if (tid == 0) {
        unsigned long long tt = 0ull, hh = 0ull;
        #pragma unroll
        for (int i = 0; i < NW; ++i) { tt += wtot[i]; hh += whigh[i]; }
        total_sum[g] = (double)tt * (1.0 / 1073741824.0);

        const int fb = s_fb;
        unsigned long long above = (fb < NB2 - 1) ? hist2[0][fb + 1] : 0ull;
        unsigned cA = (unsigned)(above >> 47);
        unsigned long long sA = above & SUMMASK;
        unsigned long long cur = hist2[0][fb];
        unsigned cf = (unsigned)(cur >> 47) - cA;
        unsigned long long sf = (cur & SUMMASK) - sA;
        // boundary fine bin: (needed-cA) items at the bin's average value.
        double take = (double)(needed - cA);
        double avg  = (cf > 0u) ? ((double)sf / (double)cf) : 0.0;
        topk_sum[g] = ((double)hh + (double)sA + take * avg) * (1.0 / 1073741824.0);
    }
}

// ---------------- Final: channel deltas + stable top-3 indices ----------------
__global__ void final_kernel(const double* __restrict__ total_sum,
                             const double* __restrict__ topk_sum,
                             int* __restrict__ out) {
    __shared__ double delta[CCH];
    const int c = threadIdx.x;
    double th = 0.0, tot = 0.0;
    for (int b = 0; b < BN; ++b) {
        th  += topk_sum[b * CCH + c];
        tot += total_sum[b * CCH + c];
    }
    // ranking monotone in (mean_high - mean)
    delta[c] = th / ((double)BN * (double)KSEL) - tot / ((double)BN * (double)HWSZ);
    __syncthreads();
    if (c == 0) {
        int chosen[3];
        for (int j = 0; j < 3; ++j) {
            double bv = -1e300; int bi = 0;
            for (int i = 0; i < CCH; ++i) {
                bool skip = false;
                for (int jj = 0; jj < j; ++jj) if (chosen[jj] == i) skip = true;
                if (!skip && delta[i] > bv) { bv = delta[i]; bi = i; }  // strict >: lower idx wins ties
            }
            chosen[j] = bi;
            out[j] = bi;
        }
    }
}

extern "C" void kernel_launch(void* const* d_in, const int* in_sizes, int n_in,
                              void* d_out, int out_size, void* d_ws, size_t ws_size,
                              hipStream_t stream) {
    const float* hsi = (const float*)d_in[0];
    const float* w   = (const float*)d_in[1];
    int* out = (int*)d_out;

    char* ws = (char*)d_ws;
    double* total_sum = (double*)(ws);          // 512*8 = 4 KB
    double* topk_sum  = (double*)(ws + 4096);   // 4 KB

    hipLaunchKernelGGL(passA_kernel, dim3(NG), dim3(NT), 0, stream, hsi, w, total_sum, topk_sum);
    hipLaunchKernelGGL(final_kernel, dim3(1), dim3(CCH), 0, stream, total_sum, topk_sum, out);
}